// Round 1
// 1229.311 us; speedup vs baseline: 1.0276x; 1.0276x over previous
//
#include <hip/hip_runtime.h>
#include <hip/hip_bf16.h>
#include <cstdint>
#include <cstddef>

#define HWIMG 13824   // H*W = 96*144
#define NTOK  110592  // B*H*W
#define CDIM  512

typedef float  floatx4  __attribute__((ext_vector_type(4)));
typedef __bf16 bf16x8   __attribute__((ext_vector_type(8)));
typedef unsigned short ushortx8 __attribute__((ext_vector_type(8)));

__device__ __forceinline__ unsigned short f2bf(float f) {
  unsigned int u = __float_as_uint(f);
  u += 0x7FFFu + ((u >> 16) & 1u);   // round-to-nearest-even
  return (unsigned short)(u >> 16);
}
__device__ __forceinline__ float bf2f(unsigned short u) {
  return __uint_as_float(((unsigned int)u) << 16);
}

#define GLL16(g, l)                                                                \
  __builtin_amdgcn_global_load_lds((const __attribute__((address_space(1))) void*)(g), \
                                   (__attribute__((address_space(3))) void*)(l), 16, 0, 0)

// ---------------------------------------------------------------------------
// K0: memory fp32 -> bf16 (row-major [m][d]) and transposed bf16 [d][m]
// ---------------------------------------------------------------------------
__global__ __launch_bounds__(256) void convert_mem_kernel(
    const float* __restrict__ mem, unsigned short* __restrict__ membf,
    unsigned short* __restrict__ memTbf) {
  int g = blockIdx.x * 256 + threadIdx.x;  // 0 .. 262143
  int m = g >> 9, d = g & 511;
  unsigned short b = f2bf(mem[g]);
  membf[g] = b;
  memTbf[d * 512 + m] = b;
}

// ---------------------------------------------------------------------------
// K1: L2-normalize over channel dim + transpose [B,C,H,W] -> qbf [N,512] bf16
// One block = 64 tokens (one b, consecutive r = h*W+w; 64 | 13824).
// ---------------------------------------------------------------------------
__global__ __launch_bounds__(256) void normalize_kernel(
    const float* __restrict__ qs, unsigned short* __restrict__ qbf) {
  __shared__ float red[4][64];
  __shared__ float inv[64];
  __shared__ float tile[64][65];  // +1 pad: conflict-free transposed reads
  const int t = threadIdx.x;
  const int n0 = blockIdx.x * 64;
  const int b = n0 / HWIMG;
  const int r0 = n0 % HWIMG;
  const float* base = qs + (size_t)b * 512 * HWIMG + r0;
  const int tok = t & 63, cp = t >> 6;

  float ssq = 0.f;
  for (int c = cp; c < 512; c += 4) {
    float x = base[(size_t)c * HWIMG + tok];   // coalesced: lanes across tok
    ssq += x * x;
  }
  red[cp][tok] = ssq;
  __syncthreads();
  if (t < 64) {
    float s = red[0][t] + red[1][t] + red[2][t] + red[3][t];
    inv[t] = 1.0f / fmaxf(sqrtf(s), 1e-12f);   // F.normalize eps semantics
  }
  __syncthreads();

  for (int cc = 0; cc < 8; cc++) {             // 8 chunks of 64 channels
#pragma unroll
    for (int i = 0; i < 16; i++) {
      int cl = (t >> 6) + i * 4;
      tile[cl][tok] = base[(size_t)(cc * 64 + cl) * HWIMG + tok];  // coalesced
    }
    __syncthreads();
    const int c_out = t & 63;
    const int tg = t >> 6;
#pragma unroll
    for (int i = 0; i < 16; i++) {
      int tk = tg * 16 + i;
      float v = tile[c_out][tk] * inv[tk];
      qbf[(size_t)(n0 + tk) * 512 + cc * 64 + c_out] = f2bf(v);    // coalesced in c
    }
    __syncthreads();
  }
}

// ---------------------------------------------------------------------------
// GEMM core (BK=64, m97 recipe): 128x128x512 per m-chunk, 256 thr = 4 waves
// (2x2 of 64x64). LDS tile chunk id c (16B units):
//   c = ((g*2 + h) << 6) | (q*16 + r15)   where row = g*16+r15 (0..127),
//   k-bytes-in-tile = h*64 + q*16  (BK=64 bf16 = 128 B/row).
// Wave reads fragment (i,h): 64 lanes hit 64 consecutive chunks -> linear,
// conflict-free ds_read_b128, and global_load_lds dest = uniform + lane*16.
// Per thread: 4 staging chunks c = t + 256*s -> row += 32/s, lds += 4096/s.
// A[n][k], B[m][k] row-major-in-k (NT gemm), K=512 -> 8 steps of 128 B.
// ---------------------------------------------------------------------------
#define GEMM_STAGE8(gAp, gBp, kb)                                          \
  GLL16((gAp) + (kb), lA);                                                 \
  GLL16((gAp) + (kb) + 32768, lA + 4096);                                  \
  GLL16((gAp) + (kb) + 65536, lA + 8192);                                  \
  GLL16((gAp) + (kb) + 98304, lA + 12288);                                 \
  GLL16((gBp) + (kb), lB);                                                 \
  GLL16((gBp) + (kb) + 32768, lB + 4096);                                  \
  GLL16((gBp) + (kb) + 65536, lB + 8192);                                  \
  GLL16((gBp) + (kb) + 98304, lB + 12288);

#define GEMM_K_LOOP(gAp, gBp)                                              \
  for (int kb = 0; kb < 1024; kb += 128) {                                 \
    GEMM_STAGE8(gAp, gBp, kb)                                              \
    asm volatile("s_waitcnt vmcnt(0)" ::: "memory");                       \
    __syncthreads();                                                       \
    _Pragma("unroll")                                                      \
    for (int h = 0; h < 2; h++) {                                          \
      bf16x8 af[4], bfv[4];                                                \
      _Pragma("unroll")                                                    \
      for (int i = 0; i < 4; i++)                                          \
        af[i] = *(const bf16x8*)&Alds[((((am + i) * 2 + h) << 6) | lane) * 8]; \
      _Pragma("unroll")                                                    \
      for (int j = 0; j < 4; j++)                                          \
        bfv[j] = *(const bf16x8*)&Blds[((((bn + j) * 2 + h) << 6) | lane) * 8]; \
      _Pragma("unroll")                                                    \
      for (int i = 0; i < 4; i++)                                          \
        _Pragma("unroll")                                                  \
        for (int j = 0; j < 4; j++)                                        \
          acc[i][j] = __builtin_amdgcn_mfma_f32_16x16x32_bf16(             \
              af[i], bfv[j], acc[i][j], 0, 0, 0);                          \
    }                                                                      \
    __syncthreads();                                                       \
  }

#define GEMM_COMMON_DECLS                                                  \
  __shared__ unsigned short Alds[128 * 64];                                \
  __shared__ unsigned short Blds[128 * 64];                                \
  const int t = threadIdx.x;                                               \
  const int lane = t & 63, wid = t >> 6;                                   \
  const int quad = lane >> 4, li = lane & 15;                              \
  const int n0 = blockIdx.x * 128;                                         \
  const int am = (wid & 1) * 4, bn = (wid >> 1) * 4;                       \
  const int wm = (wid & 1) * 64, wn = (wid >> 1) * 64;                     \
  const int row0 = ((t >> 7) << 4) | (t & 15);                             \
  const int koff = ((t >> 6) & 1) * 64 + ((t >> 4) & 3) * 16;              \
  char* lA = (char*)Alds + t * 16;                                         \
  char* lB = (char*)Blds + t * 16;

// GEMM1 (full-row): per block, S = q(128x512) . mem^T over 4 m-chunks.
// Writes Ebf = bf16(exp(S)); rowsum complete in-block (plain write);
// colsum reduced in LDS then one atomic per column per block.
__global__ __launch_bounds__(256) void gemm1_kernel(
    const unsigned short* __restrict__ A, const unsigned short* __restrict__ Bm,
    unsigned short* __restrict__ Ebf, float* __restrict__ colsum,
    float* __restrict__ rowsum) {
  __shared__ float cs_lds[512];
  __shared__ float rs_lds[128];
  GEMM_COMMON_DECLS
  cs_lds[t] = 0.f; cs_lds[t + 256] = 0.f;
  if (t < 128) rs_lds[t] = 0.f;
  const char* gA = (const char*)A + (size_t)(n0 + row0) * 1024 + koff;
  const char* gB0 = (const char*)Bm + (size_t)row0 * 1024 + koff;
  float racc[4][4];
#pragma unroll
  for (int i = 0; i < 4; i++)
#pragma unroll
    for (int r = 0; r < 4; r++) racc[i][r] = 0.f;

#pragma unroll 1
  for (int mt = 0; mt < 4; mt++) {
    floatx4 acc[4][4];
    {
      floatx4 z = {0.f, 0.f, 0.f, 0.f};
#pragma unroll
      for (int i = 0; i < 4; i++)
#pragma unroll
        for (int j = 0; j < 4; j++) acc[i][j] = z;
    }
    const char* gB = gB0 + (size_t)mt * 131072;  // 128 rows * 1024 B
    GEMM_K_LOOP(gA, gB)

    // epilogue for this m-chunk: E = exp(S) -> bf16, col/row partial sums
    float cp[4] = {0.f, 0.f, 0.f, 0.f};
#pragma unroll
    for (int i = 0; i < 4; i++) {
#pragma unroll
      for (int r = 0; r < 4; r++) {
        const int row = n0 + wm + i * 16 + quad * 4 + r;
        float rowacc = 0.f;
#pragma unroll
        for (int j = 0; j < 4; j++) {
          float e = __expf(acc[i][j][r]);  // |score|<=~1.1 -> no max shift
          const int col = mt * 128 + wn + j * 16 + li;
          Ebf[(size_t)row * 512 + col] = f2bf(e);
          cp[j] += e;
          rowacc += e;
        }
        racc[i][r] += rowacc;
      }
    }
#pragma unroll
    for (int j = 0; j < 4; j++) {
      float c = cp[j];
      c += __shfl_xor(c, 16, 64);
      c += __shfl_xor(c, 32, 64);
      if (lane < 16) atomicAdd(&cs_lds[mt * 128 + wn + j * 16 + li], c);
    }
  }

  // rowsum: reduce over li (16 lanes hold disjoint 4-col partials x 4 chunks)
#pragma unroll
  for (int i = 0; i < 4; i++) {
#pragma unroll
    for (int r = 0; r < 4; r++) {
      float v = racc[i][r];
      v += __shfl_xor(v, 1, 64);
      v += __shfl_xor(v, 2, 64);
      v += __shfl_xor(v, 4, 64);
      v += __shfl_xor(v, 8, 64);
      if (li == 0) atomicAdd(&rs_lds[wm + i * 16 + quad * 4 + r], v);
    }
  }
  __syncthreads();
  if (t < 128) rowsum[n0 + t] = rs_lds[t];          // complete: plain write
  atomicAdd(&colsum[t], cs_lds[t]);                 // one atomic/col/block
  atomicAdd(&colsum[t + 256], cs_lds[t + 256]);
}

// GEMM2 (full-row): out0[n][d] = (Ebf . memT^T)[n][d] / rowsum[n].
// The rowsum division distributes out of the GEMM -> no pbf materialization.
__global__ __launch_bounds__(256) void gemm2_kernel(
    const unsigned short* __restrict__ P, const unsigned short* __restrict__ BmT,
    const float* __restrict__ rowsum, float* __restrict__ out0) {
  GEMM_COMMON_DECLS
  const char* gA = (const char*)P + (size_t)(n0 + row0) * 1024 + koff;
  const char* gB0 = (const char*)BmT + (size_t)row0 * 1024 + koff;
  floatx4 rinv[4];
#pragma unroll
  for (int i = 0; i < 4; i++) {
    floatx4 one = {1.f, 1.f, 1.f, 1.f};
    rinv[i] = one / *(const floatx4*)&rowsum[n0 + wm + i * 16 + quad * 4];
  }
  const int bimg = n0 / HWIMG;   // 128 | 13824 -> block never straddles b
  const int r0 = n0 % HWIMG;

#pragma unroll 1
  for (int mt = 0; mt < 4; mt++) {
    floatx4 acc[4][4];
    {
      floatx4 z = {0.f, 0.f, 0.f, 0.f};
#pragma unroll
      for (int i = 0; i < 4; i++)
#pragma unroll
        for (int j = 0; j < 4; j++) acc[i][j] = z;
    }
    const char* gB = gB0 + (size_t)mt * 131072;
    GEMM_K_LOOP(gA, gB)

#pragma unroll
    for (int i = 0; i < 4; i++) {
      const int rb = r0 + wm + i * 16 + quad * 4;
#pragma unroll
      for (int j = 0; j < 4; j++) {
        const int col = mt * 128 + wn + j * 16 + li;  // = d
        *(floatx4*)&out0[(size_t)(bimg * 512 + col) * HWIMG + rb] =
            acc[i][j] * rinv[i];
      }
    }
  }
}

// ---------------------------------------------------------------------------
// K3: out1 = Ebf/colsum, out2 = Ebf/rowsum. One wave per 16 rows; lane owns
// 8 fixed columns (16 B bf16 load, 2x16 B f32 stores each, coalesced).
// ---------------------------------------------------------------------------
__global__ __launch_bounds__(256) void finalize_kernel(
    const unsigned short* __restrict__ Ebf, const float* __restrict__ colsum,
    const float* __restrict__ rowsum, float* __restrict__ out1,
    float* __restrict__ out2) {
  const int t = threadIdx.x;
  const int lane = t & 63, wid = t >> 6;
  const int rowbase = (blockIdx.x * 4 + wid) * 16;
  const int c0 = lane * 8;
  floatx4 one = {1.f, 1.f, 1.f, 1.f};
  floatx4 rc0 = one / *(const floatx4*)&colsum[c0];
  floatx4 rc1 = one / *(const floatx4*)&colsum[c0 + 4];
#pragma unroll 4
  for (int it = 0; it < 16; it++) {
    const int row = rowbase + it;
    const size_t off = (size_t)row * 512 + c0;
    ushortx8 ev = *(const ushortx8*)&Ebf[off];
    floatx4 e0, e1;
    e0[0] = bf2f(ev[0]); e0[1] = bf2f(ev[1]); e0[2] = bf2f(ev[2]); e0[3] = bf2f(ev[3]);
    e1[0] = bf2f(ev[4]); e1[1] = bf2f(ev[5]); e1[2] = bf2f(ev[6]); e1[3] = bf2f(ev[7]);
    float rr = 1.0f / rowsum[row];
    *(floatx4*)&out1[off]     = e0 * rc0;
    *(floatx4*)&out1[off + 4] = e1 * rc1;
    *(floatx4*)&out2[off]     = e0 * rr;
    *(floatx4*)&out2[off + 4] = e1 * rr;
  }
}

// ---------------------------------------------------------------------------
extern "C" void kernel_launch(void* const* d_in, const int* in_sizes, int n_in,
                              void* d_out, int out_size, void* d_ws, size_t ws_size,
                              hipStream_t stream) {
  const float* qs  = (const float*)d_in[0];   // [8,512,96,144] fp32
  const float* mem = (const float*)d_in[1];   // [512,512] fp32 (pre-normalized)

  float* out0 = (float*)d_out;                       // updated_query [8,512,96,144]
  float* out1 = out0 + (size_t)NTOK * 512;           // col-softmax (query)
  float* out2 = out1 + (size_t)NTOK * 512;           // row-softmax (memory)

  char* ws = (char*)d_ws;
  unsigned short* qbf    = (unsigned short*)ws;                    // 113,246,208 B
  unsigned short* Ebf    = (unsigned short*)(ws + 113246208);      // 113,246,208 B
  unsigned short* membf  = (unsigned short*)(ws + 226492416);      // 524,288 B
  unsigned short* memTbf = (unsigned short*)(ws + 227016704);      // 524,288 B
  float* colsum          = (float*)(ws + 227540992);               // 2,048 B
  float* rowsum          = (float*)(ws + 227543040);               // 442,368 B

  hipMemsetAsync(colsum, 0, 2048, stream);  // rowsum is plain-written now
  convert_mem_kernel<<<1024, 256, 0, stream>>>(mem, membf, memTbf);
  normalize_kernel<<<NTOK / 64, 256, 0, stream>>>(qs, qbf);
  gemm1_kernel<<<NTOK / 128, 256, 0, stream>>>(qbf, membf, Ebf, colsum, rowsum);
  finalize_kernel<<<NTOK / 64, 256, 0, stream>>>(Ebf, colsum, rowsum, out1, out2);
  gemm2_kernel<<<NTOK / 128, 256, 0, stream>>>(Ebf, memTbf, rowsum, out0);
}

// Round 2
// 1210.507 us; speedup vs baseline: 1.0436x; 1.0155x over previous
//
#include <hip/hip_runtime.h>
#include <hip/hip_bf16.h>
#include <cstdint>
#include <cstddef>

#define HWIMG 13824   // H*W = 96*144
#define NTOK  110592  // B*H*W
#define CDIM  512

typedef float  floatx4  __attribute__((ext_vector_type(4)));
typedef __bf16 bf16x8   __attribute__((ext_vector_type(8)));
typedef unsigned short ushortx8 __attribute__((ext_vector_type(8)));

__device__ __forceinline__ unsigned short f2bf(float f) {
  unsigned int u = __float_as_uint(f);
  u += 0x7FFFu + ((u >> 16) & 1u);   // round-to-nearest-even
  return (unsigned short)(u >> 16);
}
__device__ __forceinline__ float bf2f(unsigned short u) {
  return __uint_as_float(((unsigned int)u) << 16);
}

#define GLL16(g, l)                                                                \
  __builtin_amdgcn_global_load_lds((const __attribute__((address_space(1))) void*)(g), \
                                   (__attribute__((address_space(3))) void*)(l), 16, 0, 0)

// ---------------------------------------------------------------------------
// K0: memory fp32 -> bf16 (row-major [m][d]) and transposed bf16 [d][m]
// ---------------------------------------------------------------------------
__global__ __launch_bounds__(256) void convert_mem_kernel(
    const float* __restrict__ mem, unsigned short* __restrict__ membf,
    unsigned short* __restrict__ memTbf) {
  int g = blockIdx.x * 256 + threadIdx.x;  // 0 .. 262143
  int m = g >> 9, d = g & 511;
  unsigned short b = f2bf(mem[g]);
  membf[g] = b;
  memTbf[d * 512 + m] = b;
}

// ---------------------------------------------------------------------------
// K1: L2-normalize over channel dim + transpose [B,C,H,W] -> qbf [N,512] bf16
// ---------------------------------------------------------------------------
__global__ __launch_bounds__(256) void normalize_kernel(
    const float* __restrict__ qs, unsigned short* __restrict__ qbf) {
  __shared__ float red[4][64];
  __shared__ float inv[64];
  __shared__ float tile[64][65];  // +1 pad: conflict-free transposed reads
  const int t = threadIdx.x;
  const int n0 = blockIdx.x * 64;
  const int b = n0 / HWIMG;
  const int r0 = n0 % HWIMG;
  const float* base = qs + (size_t)b * 512 * HWIMG + r0;
  const int tok = t & 63, cp = t >> 6;

  float ssq = 0.f;
  for (int c = cp; c < 512; c += 4) {
    float x = base[(size_t)c * HWIMG + tok];   // coalesced: lanes across tok
    ssq += x * x;
  }
  red[cp][tok] = ssq;
  __syncthreads();
  if (t < 64) {
    float s = red[0][t] + red[1][t] + red[2][t] + red[3][t];
    inv[t] = 1.0f / fmaxf(sqrtf(s), 1e-12f);   // F.normalize eps semantics
  }
  __syncthreads();

  for (int cc = 0; cc < 8; cc++) {             // 8 chunks of 64 channels
#pragma unroll
    for (int i = 0; i < 16; i++) {
      int cl = (t >> 6) + i * 4;
      tile[cl][tok] = base[(size_t)(cc * 64 + cl) * HWIMG + tok];  // coalesced
    }
    __syncthreads();
    const int c_out = t & 63;
    const int tg = t >> 6;
#pragma unroll
    for (int i = 0; i < 16; i++) {
      int tk = tg * 16 + i;
      float v = tile[c_out][tk] * inv[tk];
      qbf[(size_t)(n0 + tk) * 512 + cc * 64 + c_out] = f2bf(v);    // coalesced in c
    }
    __syncthreads();
  }
}

// ---------------------------------------------------------------------------
// GEMM core, 2-phase double-buffered (T3 minimum recipe):
//   prologue: STAGE(buf0, s=0); vmcnt(0); barrier
//   step s  : STAGE(buf^1, s+1); MFMA from buf; vmcnt(0); barrier; [epilogues]
// Next-tile loads fly under current-tile MFMA; epilogue stores (issued after
// the barrier) drain at the NEXT step's vmcnt(0), overlapped with its loads.
// Tile 128x128, BK=64, flattened s = mt*8 + kb over full row (M=512).
// LDS chunk id c = ((g*2+h)<<6)|(q*16+r15): row=g*16+r15, kbyte=h*64+q*16 ->
// fragment reads are 64 consecutive 16B chunks (linear, conflict-free) and
// global_load_lds dest = uniform + lane*16 (wave-uniform-base rule).
// Per thread stages 4 chunks of A and B: rows row0+32*sh, col-bytes koff.
// ---------------------------------------------------------------------------
#define GEMM_DECLS                                                         \
  __shared__ unsigned short lds[32768]; /* 64 KB: [buf][A|B][8192] */      \
  const int t = threadIdx.x;                                               \
  const int lane = t & 63, wid = t >> 6;                                   \
  const int quad = lane >> 4, li = lane & 15;                              \
  const int n0 = blockIdx.x * 128;                                         \
  const int am = (wid & 1) * 4, bn = (wid >> 1) * 4;                       \
  const int wm = (wid & 1) * 64, wn = (wid >> 1) * 64;                     \
  const int row0 = ((t >> 7) << 4) | (t & 15);                             \
  const int koff = ((t >> 6) & 1) * 64 + ((t >> 4) & 3) * 16;              \
  char* ldsb = (char*)lds;

#define STAGE(buf, sidx) do {                                              \
    const char* a_ = gA + (((sidx) & 7) << 7);                             \
    const char* b_ = gB0 + (((sidx) >> 3) * 131072) + (((sidx) & 7) << 7); \
    char* la_ = ldsb + (buf) * 32768 + t * 16;                             \
    char* lb_ = la_ + 16384;                                               \
    GLL16(a_, la_);          GLL16(a_ + 32768, la_ + 4096);                \
    GLL16(a_ + 65536, la_ + 8192); GLL16(a_ + 98304, la_ + 12288);         \
    GLL16(b_, lb_);          GLL16(b_ + 32768, lb_ + 4096);                \
    GLL16(b_ + 65536, lb_ + 8192); GLL16(b_ + 98304, lb_ + 12288);         \
  } while (0)

#define COMPUTE(buf) do {                                                  \
    const unsigned short* Ac = lds + (buf) * 16384;                        \
    const unsigned short* Bc = Ac + 8192;                                  \
    _Pragma("unroll")                                                      \
    for (int h = 0; h < 2; h++) {                                          \
      bf16x8 af[4], bfv[4];                                                \
      _Pragma("unroll")                                                    \
      for (int i = 0; i < 4; i++)                                          \
        af[i] = *(const bf16x8*)&Ac[((((am + i) * 2 + h) << 6) | lane) * 8]; \
      _Pragma("unroll")                                                    \
      for (int j = 0; j < 4; j++)                                          \
        bfv[j] = *(const bf16x8*)&Bc[((((bn + j) * 2 + h) << 6) | lane) * 8]; \
      _Pragma("unroll")                                                    \
      for (int i = 0; i < 4; i++)                                          \
        _Pragma("unroll")                                                  \
        for (int j = 0; j < 4; j++)                                        \
          acc[i][j] = __builtin_amdgcn_mfma_f32_16x16x32_bf16(             \
              af[i], bfv[j], acc[i][j], 0, 0, 0);                          \
    }                                                                      \
  } while (0)

#define ACC_ZERO do {                                                     \
    floatx4 z_ = {0.f, 0.f, 0.f, 0.f};                                    \
    _Pragma("unroll")                                                     \
    for (int i = 0; i < 4; i++)                                           \
      _Pragma("unroll")                                                   \
      for (int j = 0; j < 4; j++) acc[i][j] = z_;                         \
  } while (0)

#define VMCNT0 asm volatile("s_waitcnt vmcnt(0)" ::: "memory")

// GEMM1 (full-row): S = q(128x512) . mem^T, E = exp(S) -> Ebf bf16;
// rowsum complete in-block (plain write); colsum via LDS then 1 atomic/col.
__global__ __launch_bounds__(256, 2) void gemm1_kernel(
    const unsigned short* __restrict__ A, const unsigned short* __restrict__ Bm,
    unsigned short* __restrict__ Ebf, float* __restrict__ colsum,
    float* __restrict__ rowsum) {
  GEMM_DECLS
  __shared__ float cs_lds[512];
  __shared__ float rs_lds[128];
  cs_lds[t] = 0.f; cs_lds[t + 256] = 0.f;
  if (t < 128) rs_lds[t] = 0.f;
  const char* gA = (const char*)A + (size_t)(n0 + row0) * 1024 + koff;
  const char* gB0 = (const char*)Bm + (size_t)row0 * 1024 + koff;
  float racc[4][4];
#pragma unroll
  for (int i = 0; i < 4; i++)
#pragma unroll
    for (int r = 0; r < 4; r++) racc[i][r] = 0.f;
  floatx4 acc[4][4];
  ACC_ZERO;

  STAGE(0, 0);
  VMCNT0;
  __syncthreads();
#pragma unroll 1
  for (int s = 0; s < 32; ++s) {
    const int cur = s & 1;
    if (s < 31) STAGE(cur ^ 1, s + 1);
    COMPUTE(cur);
    VMCNT0;
    __syncthreads();
    if ((s & 7) == 7) {           // mt-chunk epilogue (stores drain next step)
      const int mt = s >> 3;
      float cp[4] = {0.f, 0.f, 0.f, 0.f};
#pragma unroll
      for (int i = 0; i < 4; i++) {
#pragma unroll
        for (int r = 0; r < 4; r++) {
          const int row = n0 + wm + i * 16 + quad * 4 + r;
          float rowacc = 0.f;
#pragma unroll
          for (int j = 0; j < 4; j++) {
            float e = __expf(acc[i][j][r]);  // |score|<=~1.1 -> no max shift
            const int col = mt * 128 + wn + j * 16 + li;
            Ebf[(size_t)row * 512 + col] = f2bf(e);
            cp[j] += e;
            rowacc += e;
          }
          racc[i][r] += rowacc;
        }
      }
#pragma unroll
      for (int j = 0; j < 4; j++) {
        float c = cp[j];
        c += __shfl_xor(c, 16, 64);
        c += __shfl_xor(c, 32, 64);
        if (lane < 16) atomicAdd(&cs_lds[mt * 128 + wn + j * 16 + li], c);
      }
      ACC_ZERO;
    }
  }

  // rowsum: reduce over li (16 lanes hold disjoint 4-col partials x 4 chunks)
#pragma unroll
  for (int i = 0; i < 4; i++) {
#pragma unroll
    for (int r = 0; r < 4; r++) {
      float v = racc[i][r];
      v += __shfl_xor(v, 1, 64);
      v += __shfl_xor(v, 2, 64);
      v += __shfl_xor(v, 4, 64);
      v += __shfl_xor(v, 8, 64);
      if (li == 0) atomicAdd(&rs_lds[wm + i * 16 + quad * 4 + r], v);
    }
  }
  __syncthreads();
  if (t < 128) rowsum[n0 + t] = rs_lds[t];          // complete: plain write
  atomicAdd(&colsum[t], cs_lds[t]);                 // one atomic/col/block
  atomicAdd(&colsum[t + 256], cs_lds[t + 256]);
}

// GEMM2 (full-row) + fused finalize: out0 = (Ebf . memT^T)/rowsum, and while
// each Ebf A-tile sits in LDS (steps s=0..7 cover all of Ebf[block]), scale it
// by precomputed 1/colsum, 1/rowsum -> out1, out2. finalize kernel eliminated.
__global__ __launch_bounds__(256, 2) void gemm2_kernel(
    const unsigned short* __restrict__ P, const unsigned short* __restrict__ BmT,
    const float* __restrict__ rowsum, const float* __restrict__ colsum,
    float* __restrict__ out0, float* __restrict__ out1, float* __restrict__ out2) {
  GEMM_DECLS
  __shared__ __align__(16) float inv_cs[512];
  __shared__ __align__(16) float inv_rs[128];
  inv_cs[t] = 1.0f / colsum[t];
  inv_cs[t + 256] = 1.0f / colsum[t + 256];
  if (t < 128) inv_rs[t] = 1.0f / rowsum[n0 + t];
  const char* gA = (const char*)P + (size_t)(n0 + row0) * 1024 + koff;
  const char* gB0 = (const char*)BmT + (size_t)row0 * 1024 + koff;
  const int bimg = n0 / HWIMG;   // 128 | 13824 -> block never straddles b
  const int r0 = n0 % HWIMG;
  floatx4 acc[4][4];
  ACC_ZERO;

  STAGE(0, 0);
  VMCNT0;
  __syncthreads();               // also publishes inv_cs / inv_rs
#pragma unroll 1
  for (int s = 0; s < 32; ++s) {
    const int cur = s & 1;
    if (s < 31) STAGE(cur ^ 1, s + 1);
    COMPUTE(cur);
    VMCNT0;
    __syncthreads();
    if (s < 8) {                 // fused finalize: buf[cur] A-region is all of
      const int cbase = s * 64 + (koff >> 1);   // Ebf[block] over s=0..7
      const floatx4 rca = *(const floatx4*)&inv_cs[cbase];
      const floatx4 rcb = *(const floatx4*)&inv_cs[cbase + 4];
#pragma unroll
      for (int sh = 0; sh < 4; ++sh) {
        ushortx8 ev = *(const ushortx8*)(ldsb + cur * 32768 + t * 16 + sh * 4096);
        const float rr = inv_rs[row0 + 32 * sh];
        floatx4 e0, e1;
        e0[0] = bf2f(ev[0]); e0[1] = bf2f(ev[1]); e0[2] = bf2f(ev[2]); e0[3] = bf2f(ev[3]);
        e1[0] = bf2f(ev[4]); e1[1] = bf2f(ev[5]); e1[2] = bf2f(ev[6]); e1[3] = bf2f(ev[7]);
        const size_t off = (size_t)(n0 + row0 + 32 * sh) * 512 + cbase;
        *(floatx4*)&out1[off]     = e0 * rca;
        *(floatx4*)&out1[off + 4] = e1 * rcb;
        *(floatx4*)&out2[off]     = e0 * rr;
        *(floatx4*)&out2[off + 4] = e1 * rr;
      }
    }
    if ((s & 7) == 7) {          // out0 epilogue for this m-chunk
      const int mt = s >> 3;
#pragma unroll
      for (int i = 0; i < 4; i++) {
        const int rb = r0 + wm + i * 16 + quad * 4;
        const floatx4 riv = *(const floatx4*)&inv_rs[wm + i * 16 + quad * 4];
#pragma unroll
        for (int j = 0; j < 4; j++) {
          const int col = mt * 128 + wn + j * 16 + li;  // = d
          *(floatx4*)&out0[(size_t)(bimg * 512 + col) * HWIMG + rb] =
              acc[i][j] * riv;
        }
      }
      ACC_ZERO;
    }
  }
}

// ---------------------------------------------------------------------------
extern "C" void kernel_launch(void* const* d_in, const int* in_sizes, int n_in,
                              void* d_out, int out_size, void* d_ws, size_t ws_size,
                              hipStream_t stream) {
  const float* qs  = (const float*)d_in[0];   // [8,512,96,144] fp32
  const float* mem = (const float*)d_in[1];   // [512,512] fp32 (pre-normalized)

  float* out0 = (float*)d_out;                       // updated_query [8,512,96,144]
  float* out1 = out0 + (size_t)NTOK * 512;           // col-softmax (query)
  float* out2 = out1 + (size_t)NTOK * 512;           // row-softmax (memory)

  char* ws = (char*)d_ws;
  unsigned short* qbf    = (unsigned short*)ws;                    // 113,246,208 B
  unsigned short* Ebf    = (unsigned short*)(ws + 113246208);      // 113,246,208 B
  unsigned short* membf  = (unsigned short*)(ws + 226492416);      // 524,288 B
  unsigned short* memTbf = (unsigned short*)(ws + 227016704);      // 524,288 B
  float* colsum          = (float*)(ws + 227540992);               // 2,048 B
  float* rowsum          = (float*)(ws + 227543040);               // 442,368 B

  hipMemsetAsync(colsum, 0, 2048, stream);  // rowsum is plain-written by gemm1
  convert_mem_kernel<<<1024, 256, 0, stream>>>(mem, membf, memTbf);
  normalize_kernel<<<NTOK / 64, 256, 0, stream>>>(qs, qbf);
  gemm1_kernel<<<NTOK / 128, 256, 0, stream>>>(qbf, membf, Ebf, colsum, rowsum);
  gemm2_kernel<<<NTOK / 128, 256, 0, stream>>>(Ebf, memTbf, rowsum, colsum,
                                               out0, out1, out2);
}